// Round 5
// baseline (57089.020 us; speedup 1.0000x reference)
//
#include <hip/hip_runtime.h>
#include <hip/hip_bf16.h>

#define TSTEPS 512
#define NSTEPS 256          // steps per chunk
#define BATCH  64
#define HDIM   1024
#define NROWS  (TSTEPS*BATCH)   // 32768

typedef __attribute__((ext_vector_type(8))) short bf16x8;
typedef __attribute__((ext_vector_type(4))) float f32x4;

__device__ __forceinline__ unsigned short f2bf(float f){
    unsigned u = __float_as_uint(f);
    u += 0x7fffu + ((u >> 16) & 1u);
    return (unsigned short)(u >> 16);
}
__device__ __forceinline__ float bf2f(unsigned short s){
    return __uint_as_float(((unsigned)s) << 16);
}

// ---------------------------------------------------------------------------
// Broadcast tree barrier, O(1) contention depth.
// Region layout (uint words): slots[256] at +0, release word at +320.
// Epochs are monotonically increasing within one kernel instance; each
// kernel instance gets its own region (no cross-instance reuse).
// ---------------------------------------------------------------------------
__device__ __forceinline__ void gridbar(unsigned int* region, unsigned int epoch){
    unsigned int* slots = region;
    unsigned int* rel   = region + 320;
    __syncthreads();
    __builtin_amdgcn_fence(__ATOMIC_RELEASE, "agent");   // make h stores visible (wb L2)
    if (blockIdx.x == 0){
        const int i = threadIdx.x;
        if (i > 0){  // poll slot i (blocks 1..255), one slot per thread
            while (__hip_atomic_load(&slots[i], __ATOMIC_RELAXED, __HIP_MEMORY_SCOPE_AGENT) < epoch)
                __builtin_amdgcn_s_sleep(2);
        }
        __builtin_amdgcn_fence(__ATOMIC_ACQUIRE, "agent");
        __syncthreads();
        if (i == 0)
            __hip_atomic_store(rel, epoch, __ATOMIC_RELAXED, __HIP_MEMORY_SCOPE_AGENT);
    } else {
        if (threadIdx.x == 0){
            __hip_atomic_store(&slots[blockIdx.x], epoch, __ATOMIC_RELAXED, __HIP_MEMORY_SCOPE_AGENT);
            while (__hip_atomic_load(rel, __ATOMIC_RELAXED, __HIP_MEMORY_SCOPE_AGENT) < epoch)
                __builtin_amdgcn_s_sleep(4);
        }
        __syncthreads();
    }
    __builtin_amdgcn_fence(__ATOMIC_ACQUIRE, "agent");   // inv caches before h reads
}

// ---------------------------------------------------------------------------
// W [1024][4096] fp32 -> WThi/WTlo [4096][1024] bf16 (transpose + split)
// ---------------------------------------------------------------------------
__global__ __launch_bounds__(256)
void split_transpose_w(const float* __restrict__ W,
                       unsigned short* __restrict__ WThi,
                       unsigned short* __restrict__ WTlo)
{
    __shared__ float tile[32][33];
    const int c0 = blockIdx.x * 32;
    const int k0 = blockIdx.y * 32;
    const int tx = threadIdx.x & 31, ty = threadIdx.x >> 5;
    #pragma unroll
    for (int r=0;r<4;++r)
        tile[ty + r*8][tx] = W[(size_t)(k0 + ty + r*8)*4096 + c0 + tx];
    __syncthreads();
    #pragma unroll
    for (int r=0;r<4;++r){
        float v = tile[tx][ty + r*8];
        unsigned short hi = f2bf(v);
        unsigned short lo = f2bf(v - bf2f(hi));
        WThi[(size_t)(c0 + ty + r*8)*1024 + k0 + tx] = hi;
        WTlo[(size_t)(c0 + ty + r*8)*1024 + k0 + tx] = lo;
    }
}

// ---------------------------------------------------------------------------
// Split-bf16 MFMA GEMM over one 16384-row chunk (unchanged from round 4):
//   gp[t][bid][b][j] = sum_k A[row][k]*W[k][col] + bias[col]
// ---------------------------------------------------------------------------
__global__ __launch_bounds__(256)
void gemm_xw_split(const float* __restrict__ A,
                   const unsigned short* __restrict__ BThi,
                   const unsigned short* __restrict__ BTlo,
                   const float* __restrict__ bias, float* __restrict__ gp)
{
    __shared__ __align__(16) unsigned short Ahi[128*32];
    __shared__ __align__(16) unsigned short Alo[128*32];
    __shared__ __align__(16) unsigned short Bhi[128*32];
    __shared__ __align__(16) unsigned short Blo[128*32];

    const int tid = threadIdx.x;
    const int w = tid >> 6, l = tid & 63;
    const int bx = blockIdx.x & 31, by = blockIdx.x >> 5;
    const int row0 = by*128, col0 = bx*128;
    const int wrow = (w>>1)*64, wcol = (w&1)*64;

    const int srow  = l >> 2;
    const int skoff = (l & 3) * 8;

    const int arow  = tid >> 1;
    const int akoff = (tid & 1) * 16;
    const float* aptr = A + (size_t)(row0 + arow)*1024 + akoff;

    f32x4 acc[4][4];
    #pragma unroll
    for (int m=0;m<4;++m)
        #pragma unroll
        for (int n=0;n<4;++n)
            acc[m][n] = (f32x4){0.f,0.f,0.f,0.f};

    for (int k0=0; k0<1024; k0+=32){
        #pragma unroll
        for (int c=0;c<2;++c){
            const int i = w*2 + c;
            const unsigned short* gh = BThi + (size_t)(col0 + i*16 + srow)*1024 + k0 + skoff;
            const unsigned short* gl = BTlo + (size_t)(col0 + i*16 + srow)*1024 + k0 + skoff;
            __builtin_amdgcn_global_load_lds((const __attribute__((address_space(1))) void*)gh,
                (__attribute__((address_space(3))) void*)(Bhi + i*512), 16, 0, 0);
            __builtin_amdgcn_global_load_lds((const __attribute__((address_space(1))) void*)gl,
                (__attribute__((address_space(3))) void*)(Blo + i*512), 16, 0, 0);
        }
        {
            float4 x0 = *reinterpret_cast<const float4*>(aptr + k0);
            float4 x1 = *reinterpret_cast<const float4*>(aptr + k0 + 4);
            float4 x2 = *reinterpret_cast<const float4*>(aptr + k0 + 8);
            float4 x3 = *reinterpret_cast<const float4*>(aptr + k0 + 12);
            float xs[16] = {x0.x,x0.y,x0.z,x0.w, x1.x,x1.y,x1.z,x1.w,
                            x2.x,x2.y,x2.z,x2.w, x3.x,x3.y,x3.z,x3.w};
            unsigned short hs[16], ls[16];
            #pragma unroll
            for (int e=0;e<16;++e){
                hs[e] = f2bf(xs[e]);
                ls[e] = f2bf(xs[e] - bf2f(hs[e]));
            }
            #pragma unroll
            for (int q=0;q<4;++q){
                ushort4 h4; h4.x=hs[q*4]; h4.y=hs[q*4+1]; h4.z=hs[q*4+2]; h4.w=hs[q*4+3];
                ushort4 l4; l4.x=ls[q*4]; l4.y=ls[q*4+1]; l4.z=ls[q*4+2]; l4.w=ls[q*4+3];
                *reinterpret_cast<ushort4*>(&Ahi[arow*32 + akoff + q*4]) = h4;
                *reinterpret_cast<ushort4*>(&Alo[arow*32 + akoff + q*4]) = l4;
            }
        }
        __syncthreads();
        bf16x8 afh[4], afl[4], bfh[4], bfl[4];
        #pragma unroll
        for (int m=0;m<4;++m){
            const int off = (wrow + m*16 + (l&15))*32 + (l>>4)*8;
            afh[m] = *reinterpret_cast<const bf16x8*>(&Ahi[off]);
            afl[m] = *reinterpret_cast<const bf16x8*>(&Alo[off]);
        }
        #pragma unroll
        for (int n=0;n<4;++n){
            const int off = (wcol + n*16 + (l&15))*32 + (l>>4)*8;
            bfh[n] = *reinterpret_cast<const bf16x8*>(&Bhi[off]);
            bfl[n] = *reinterpret_cast<const bf16x8*>(&Blo[off]);
        }
        #pragma unroll
        for (int m=0;m<4;++m)
            #pragma unroll
            for (int n=0;n<4;++n){
                acc[m][n] = __builtin_amdgcn_mfma_f32_16x16x32_bf16(afh[m], bfh[n], acc[m][n], 0,0,0);
                acc[m][n] = __builtin_amdgcn_mfma_f32_16x16x32_bf16(afl[m], bfh[n], acc[m][n], 0,0,0);
                acc[m][n] = __builtin_amdgcn_mfma_f32_16x16x32_bf16(afh[m], bfl[n], acc[m][n], 0,0,0);
            }
        __syncthreads();
    }

    #pragma unroll
    for (int n=0;n<4;++n){
        const int n_g = col0 + wcol + n*16 + (l&15);
        const float bv = bias[n_g];
        const int g = n_g >> 10, hcol = n_g & 1023;
        const int bid = hcol >> 2, hj = hcol & 3;
        #pragma unroll
        for (int m=0;m<4;++m){
            #pragma unroll
            for (int r=0;r<4;++r){
                const int m_g = row0 + wrow + m*16 + (l>>4)*4 + r;
                const int t = m_g >> 6, b = m_g & 63;
                gp[(((size_t)t*256 + bid)*64 + b)*16 + g*4 + hj] = acc[m][n][r] + bv;
            }
        }
    }
}

// ---------------------------------------------------------------------------
// Persistent recurrence over one 256-step chunk — ALL fp32 (round-4 logic,
// new barrier). Block owns h-cols [bidx*4, bidx*4+4).
// ---------------------------------------------------------------------------
__global__ __launch_bounds__(256)
void lstm_seq(const float* __restrict__ gp, const float* __restrict__ Whh,
              float* __restrict__ out, float* __restrict__ hta,
              float* __restrict__ htb, float* __restrict__ ctg,
              float* __restrict__ hn, float* __restrict__ cn,
              unsigned int* __restrict__ bar, int first, int last)
{
    __shared__ float Wlds[1024*16];        // 64 KB [k][j]
    __shared__ float hstage[4][2][2048];   // 64 KB per-wave dbuf [32k][64b]
    __shared__ float pacc[4][64*17];       // padded partial gates [b][j]
    __shared__ float xwlds[64*17];         // padded xW slice [b][j]
    __shared__ float ctl[256];             // c state [hj*64+b]
    __shared__ float hout[256];            // h_new [b*4+hj]

    const int tid  = threadIdx.x;
    const int bidx = blockIdx.x;
    const int w = tid >> 6, l = tid & 63;

    {   // W_hh slice: Wlds[k][j] = Whh[k][(j/4)*1024 + bidx*4 + (j%4)]
        const int j = tid & 15;
        const int col = (j>>2)*1024 + bidx*4 + (j&3);
        for (int k = tid>>4; k < 1024; k += 16)
            Wlds[k*16 + j] = Whh[(size_t)k*4096 + col];
    }
    ctl[tid] = first ? 0.f : ctg[bidx*256 + tid];
    if (first){
        const int hcolg = bidx*4 + (tid>>6);
        hta[hcolg*64 + (tid&63)] = 0.f;
        gridbar(bar, 1);
    }

    float* hcur = hta;
    float* hnxt = htb;

    const int c0 = (l & 3) << 2;
    const int b0 = (l >> 2) << 2;
    const int kbase = w << 8;
    const int bq = tid & 63;
    const int hj = tid >> 6;

    for (int t=0; t<NSTEPS; ++t){
        {   // xW[t] slice -> xwlds (padded [b][j], stride 17)
            float4 v = *reinterpret_cast<const float4*>(gp + ((size_t)t*256 + bidx)*1024 + tid*4);
            const int b = tid >> 2, j0 = (tid & 3)*4;
            float* xp = &xwlds[b*17 + j0];
            xp[0]=v.x; xp[1]=v.y; xp[2]=v.z; xp[3]=v.w;
        }

        const float* hc = hcur + (size_t)kbase*64;
        float4 pre[8];
        #pragma unroll
        for (int it=0;it<8;++it)
            pre[it] = *reinterpret_cast<const float4*>(hc + it*256 + l*4);
        #pragma unroll
        for (int it=0;it<8;++it)
            *reinterpret_cast<float4*>(&hstage[w][0][it*256 + l*4]) = pre[it];

        float acc[4][4];
        #pragma unroll
        for (int i2=0;i2<4;++i2){acc[i2][0]=0.f;acc[i2][1]=0.f;acc[i2][2]=0.f;acc[i2][3]=0.f;}

        for (int sc=0; sc<8; ++sc){
            if (sc < 7){
                const float* s2 = hc + (size_t)(sc+1)*2048;
                #pragma unroll
                for (int it=0;it<8;++it)
                    pre[it] = *reinterpret_cast<const float4*>(s2 + it*256 + l*4);
            }
            const float* hs = hstage[w][sc&1];
            const float* wl = &Wlds[(size_t)(kbase + sc*32)*16];
            #pragma unroll
            for (int kk=0; kk<32; ++kk){
                float4 hv = *reinterpret_cast<const float4*>(&hs[kk*64 + b0]);
                float4 wv = *reinterpret_cast<const float4*>(&wl[kk*16 + c0]);
                acc[0][0]+=hv.x*wv.x; acc[0][1]+=hv.x*wv.y; acc[0][2]+=hv.x*wv.z; acc[0][3]+=hv.x*wv.w;
                acc[1][0]+=hv.y*wv.x; acc[1][1]+=hv.y*wv.y; acc[1][2]+=hv.y*wv.z; acc[1][3]+=hv.y*wv.w;
                acc[2][0]+=hv.z*wv.x; acc[2][1]+=hv.z*wv.y; acc[2][2]+=hv.z*wv.z; acc[2][3]+=hv.z*wv.w;
                acc[3][0]+=hv.w*wv.x; acc[3][1]+=hv.w*wv.y; acc[3][2]+=hv.w*wv.z; acc[3][3]+=hv.w*wv.w;
            }
            if (sc < 7){
                float* d = hstage[w][(sc+1)&1];
                #pragma unroll
                for (int it=0;it<8;++it)
                    *reinterpret_cast<float4*>(&d[it*256 + l*4]) = pre[it];
            }
        }
        #pragma unroll
        for (int bi=0;bi<4;++bi){
            float* pp = &pacc[w][(b0+bi)*17 + c0];
            pp[0]=acc[bi][0]; pp[1]=acc[bi][1]; pp[2]=acc[bi][2]; pp[3]=acc[bi][3];
        }
        __syncthreads();

        {   // phase C: one thread per (batch, h-col)
            float gs[4];
            #pragma unroll
            for (int g=0; g<4; ++g){
                const int idx = bq*17 + g*4 + hj;
                gs[g] = xwlds[idx] + pacc[0][idx] + pacc[1][idx] + pacc[2][idx] + pacc[3][idx];
            }
            float ig = 1.f/(1.f + __expf(-gs[0]));
            float fg = 1.f/(1.f + __expf(-gs[1]));
            float gg = tanhf(gs[2]);
            float og = 1.f/(1.f + __expf(-gs[3]));
            float c_new = fg * ctl[hj*64 + bq] + ig * gg;
            float h_new = og * tanhf(c_new);
            ctl[hj*64 + bq] = c_new;
            const int hcolg = bidx*4 + hj;
            hnxt[hcolg*64 + bq] = h_new;
            hout[bq*4 + hj] = h_new;
            if (last && t == NSTEPS-1){
                hn[(size_t)bq*1024 + hcolg] = h_new;
                cn[(size_t)bq*1024 + hcolg] = c_new;
            }
        }
        __syncthreads();
        if (tid < 64){
            float4 hv = *reinterpret_cast<const float4*>(&hout[tid*4]);
            *reinterpret_cast<float4*>(&out[(size_t)t*65536 + (size_t)tid*1024 + bidx*4]) = hv;
        }
        gridbar(bar, t + 2);
        float* tmp = hcur; hcur = hnxt; hnxt = tmp;
    }
    ctg[bidx*256 + tid] = ctl[tid];
}

// ---------------------------------------------------------------------------
extern "C" void kernel_launch(void* const* d_in, const int* in_sizes, int n_in,
                              void* d_out, int out_size, void* d_ws, size_t ws_size,
                              hipStream_t stream)
{
    const float* x    = (const float*)d_in[0];
    const float* Wih0 = (const float*)d_in[1];
    const float* Whh0 = (const float*)d_in[2];
    const float* b0   = (const float*)d_in[3];
    const float* Wih1 = (const float*)d_in[4];
    const float* Whh1 = (const float*)d_in[5];
    const float* b1   = (const float*)d_in[6];

    float* out1 = (float*)d_out;
    float* hn   = out1 + (size_t)NROWS*HDIM;      // [2][64][1024]
    float* cn   = hn + 2*BATCH*HDIM;

    // layer-0 output scratch aliases out1 (safe: each out0 chunk is consumed
    // by the layer-1 GEMM before the layer-1 recurrence overwrites it).
    float* out0 = out1;

    char* wsb = (char*)d_ws;
    float*          gp    = (float*)wsb;                               // 268,435,456 B
    unsigned short* WThi0 = (unsigned short*)(wsb + 268435456ull);     //   8,388,608
    unsigned short* WTlo0 = (unsigned short*)(wsb + 276824064ull);     //   8,388,608
    unsigned short* WThi1 = (unsigned short*)(wsb + 285212672ull);     //   8,388,608
    unsigned short* WTlo1 = (unsigned short*)(wsb + 293601280ull);     //   8,388,608
    float*          hta   = (float*)(wsb + 301989888ull);              //     262,144
    float*          htb   = (float*)(wsb + 302252032ull);              //     262,144
    float*          ctg   = (float*)(wsb + 302514176ull);              //     262,144
    unsigned int*   bar   = (unsigned int*)(wsb + 302776320ull);       //       8,192

    hipMemsetAsync(bar, 0, 4*512*sizeof(unsigned int), stream);
    split_transpose_w<<<dim3(128,32),256,0,stream>>>(Wih0, WThi0, WTlo0);
    split_transpose_w<<<dim3(128,32),256,0,stream>>>(Wih1, WThi1, WTlo1);

    const float*          Ain [2] = {x, out0};
    const unsigned short* Whi [2] = {WThi0, WThi1};
    const unsigned short* Wlo [2] = {WTlo0, WTlo1};
    const float*          bia [2] = {b0, b1};
    const float*          whh [2] = {Whh0, Whh1};
    float*                outp[2] = {out0, out1};

    for (int layer=0; layer<2; ++layer){
        for (int chunk=0; chunk<2; ++chunk){
            gemm_xw_split<<<4096,256,0,stream>>>(
                Ain[layer] + (size_t)chunk*NSTEPS*BATCH*HDIM,
                Whi[layer], Wlo[layer], bia[layer], gp);

            const float* gpc = gp; const float* wh = whh[layer];
            float* op = outp[layer] + (size_t)chunk*NSTEPS*BATCH*HDIM;
            float* ha = hta; float* hb = htb; float* cg_ = ctg;
            float* h_ = hn + (size_t)layer*BATCH*HDIM;
            float* c_ = cn + (size_t)layer*BATCH*HDIM;
            unsigned int* br = bar + (size_t)(layer*2 + chunk)*512;
            int first = (chunk == 0), last = (chunk == 1);
            void* args[11] = {(void*)&gpc, (void*)&wh, (void*)&op, (void*)&ha,
                              (void*)&hb, (void*)&cg_, (void*)&h_, (void*)&c_,
                              (void*)&br, (void*)&first, (void*)&last};
            hipLaunchCooperativeKernel(reinterpret_cast<void*>(&lstm_seq),
                                       dim3(256), dim3(256), args, 0, stream);
        }
    }
}

// Round 8
// 40053.091 us; speedup vs baseline: 1.4253x; 1.4253x over previous
//
#include <hip/hip_runtime.h>
#include <hip/hip_bf16.h>

#define TSTEPS 512
#define NSTEPS 256          // steps per chunk
#define BATCH  64
#define HDIM   1024
#define NROWS  (TSTEPS*BATCH)   // 32768

typedef __attribute__((ext_vector_type(8))) short bf16x8;
typedef __attribute__((ext_vector_type(4))) float f32x4;

__device__ __forceinline__ unsigned short f2bf(float f){
    unsigned u = __float_as_uint(f);
    u += 0x7fffu + ((u >> 16) & 1u);
    return (unsigned short)(u >> 16);
}
__device__ __forceinline__ float bf2f(unsigned short s){
    return __uint_as_float(((unsigned)s) << 16);
}

// ---------------------------------------------------------------------------
// W [1024][4096] fp32 -> WThi/WTlo [4096][1024] bf16 (transpose + split)
// ---------------------------------------------------------------------------
__global__ __launch_bounds__(256)
void split_transpose_w(const float* __restrict__ W,
                       unsigned short* __restrict__ WThi,
                       unsigned short* __restrict__ WTlo)
{
    __shared__ float tile[32][33];
    const int c0 = blockIdx.x * 32;
    const int k0 = blockIdx.y * 32;
    const int tx = threadIdx.x & 31, ty = threadIdx.x >> 5;
    #pragma unroll
    for (int r=0;r<4;++r)
        tile[ty + r*8][tx] = W[(size_t)(k0 + ty + r*8)*4096 + c0 + tx];
    __syncthreads();
    #pragma unroll
    for (int r=0;r<4;++r){
        float v = tile[tx][ty + r*8];
        unsigned short hi = f2bf(v);
        unsigned short lo = f2bf(v - bf2f(hi));
        WThi[(size_t)(c0 + ty + r*8)*1024 + k0 + tx] = hi;
        WTlo[(size_t)(c0 + ty + r*8)*1024 + k0 + tx] = lo;
    }
}

// ---------------------------------------------------------------------------
// W_hh [1024][4096] fp32 -> WhhR [256][1024][16] fp32, block-contiguous:
// WhhR[bid][k][j] = Whh[k][ (j>>2)*1024 + bid*4 + (j&3) ]  (one-time prep)
// ---------------------------------------------------------------------------
__global__ __launch_bounds__(256)
void reorder_whh(const float* __restrict__ W, float* __restrict__ Wr)
{
    const int bid = blockIdx.x;
    const int tid = threadIdx.x;
    #pragma unroll
    for (int kk=0; kk<4; ++kk){
        const int k = tid*4 + kk;
        float* dst = Wr + ((size_t)bid*1024 + k)*16;
        #pragma unroll
        for (int j=0;j<16;++j)
            dst[j] = W[(size_t)k*4096 + (j>>2)*1024 + bid*4 + (j&3)];
    }
}

// ---------------------------------------------------------------------------
// Split-bf16 MFMA GEMM over one 16384-row chunk (unchanged, proven):
//   gp[t][bid][b][j] = sum_k A[row][k]*W[k][col] + bias[col]
// ---------------------------------------------------------------------------
__global__ __launch_bounds__(256)
void gemm_xw_split(const float* __restrict__ A,
                   const unsigned short* __restrict__ BThi,
                   const unsigned short* __restrict__ BTlo,
                   const float* __restrict__ bias, float* __restrict__ gp)
{
    __shared__ __align__(16) unsigned short Ahi[128*32];
    __shared__ __align__(16) unsigned short Alo[128*32];
    __shared__ __align__(16) unsigned short Bhi[128*32];
    __shared__ __align__(16) unsigned short Blo[128*32];

    const int tid = threadIdx.x;
    const int w = tid >> 6, l = tid & 63;
    const int bx = blockIdx.x & 31, by = blockIdx.x >> 5;
    const int row0 = by*128, col0 = bx*128;
    const int wrow = (w>>1)*64, wcol = (w&1)*64;

    const int srow  = l >> 2;
    const int skoff = (l & 3) * 8;

    const int arow  = tid >> 1;
    const int akoff = (tid & 1) * 16;
    const float* aptr = A + (size_t)(row0 + arow)*1024 + akoff;

    f32x4 acc[4][4];
    #pragma unroll
    for (int m=0;m<4;++m)
        #pragma unroll
        for (int n=0;n<4;++n)
            acc[m][n] = (f32x4){0.f,0.f,0.f,0.f};

    for (int k0=0; k0<1024; k0+=32){
        #pragma unroll
        for (int c=0;c<2;++c){
            const int i = w*2 + c;
            const unsigned short* gh = BThi + (size_t)(col0 + i*16 + srow)*1024 + k0 + skoff;
            const unsigned short* gl = BTlo + (size_t)(col0 + i*16 + srow)*1024 + k0 + skoff;
            __builtin_amdgcn_global_load_lds((const __attribute__((address_space(1))) void*)gh,
                (__attribute__((address_space(3))) void*)(Bhi + i*512), 16, 0, 0);
            __builtin_amdgcn_global_load_lds((const __attribute__((address_space(1))) void*)gl,
                (__attribute__((address_space(3))) void*)(Blo + i*512), 16, 0, 0);
        }
        {
            float4 x0 = *reinterpret_cast<const float4*>(aptr + k0);
            float4 x1 = *reinterpret_cast<const float4*>(aptr + k0 + 4);
            float4 x2 = *reinterpret_cast<const float4*>(aptr + k0 + 8);
            float4 x3 = *reinterpret_cast<const float4*>(aptr + k0 + 12);
            float xs[16] = {x0.x,x0.y,x0.z,x0.w, x1.x,x1.y,x1.z,x1.w,
                            x2.x,x2.y,x2.z,x2.w, x3.x,x3.y,x3.z,x3.w};
            unsigned short hs[16], ls[16];
            #pragma unroll
            for (int e=0;e<16;++e){
                hs[e] = f2bf(xs[e]);
                ls[e] = f2bf(xs[e] - bf2f(hs[e]));
            }
            #pragma unroll
            for (int q=0;q<4;++q){
                ushort4 h4; h4.x=hs[q*4]; h4.y=hs[q*4+1]; h4.z=hs[q*4+2]; h4.w=hs[q*4+3];
                ushort4 l4; l4.x=ls[q*4]; l4.y=ls[q*4+1]; l4.z=ls[q*4+2]; l4.w=ls[q*4+3];
                *reinterpret_cast<ushort4*>(&Ahi[arow*32 + akoff + q*4]) = h4;
                *reinterpret_cast<ushort4*>(&Alo[arow*32 + akoff + q*4]) = l4;
            }
        }
        __syncthreads();
        bf16x8 afh[4], afl[4], bfh[4], bfl[4];
        #pragma unroll
        for (int m=0;m<4;++m){
            const int off = (wrow + m*16 + (l&15))*32 + (l>>4)*8;
            afh[m] = *reinterpret_cast<const bf16x8*>(&Ahi[off]);
            afl[m] = *reinterpret_cast<const bf16x8*>(&Alo[off]);
        }
        #pragma unroll
        for (int n=0;n<4;++n){
            const int off = (wcol + n*16 + (l&15))*32 + (l>>4)*8;
            bfh[n] = *reinterpret_cast<const bf16x8*>(&Bhi[off]);
            bfl[n] = *reinterpret_cast<const bf16x8*>(&Blo[off]);
        }
        #pragma unroll
        for (int m=0;m<4;++m)
            #pragma unroll
            for (int n=0;n<4;++n){
                acc[m][n] = __builtin_amdgcn_mfma_f32_16x16x32_bf16(afh[m], bfh[n], acc[m][n], 0,0,0);
                acc[m][n] = __builtin_amdgcn_mfma_f32_16x16x32_bf16(afl[m], bfh[n], acc[m][n], 0,0,0);
                acc[m][n] = __builtin_amdgcn_mfma_f32_16x16x32_bf16(afh[m], bfl[n], acc[m][n], 0,0,0);
            }
        __syncthreads();
    }

    #pragma unroll
    for (int n=0;n<4;++n){
        const int n_g = col0 + wcol + n*16 + (l&15);
        const float bv = bias[n_g];
        const int g = n_g >> 10, hcol = n_g & 1023;
        const int bid = hcol >> 2, hj = hcol & 3;
        #pragma unroll
        for (int m=0;m<4;++m){
            #pragma unroll
            for (int r=0;r<4;++r){
                const int m_g = row0 + wrow + m*16 + (l>>4)*4 + r;
                const int t = m_g >> 6, b = m_g & 63;
                gp[(((size_t)t*256 + bid)*64 + b)*16 + g*4 + hj] = acc[m][n][r] + bv;
            }
        }
    }
}

// ---------------------------------------------------------------------------
// ONE time step. Plain kernel; kernel boundary provides all coherence.
// Block owns h-cols [bidx*4, bidx*4+4). W_hh slice (64 KB, block-contiguous
// in WhhR) staged to LDS via global_load_lds. c-state in ctg global.
// Arithmetic identical to the proven r4 lstm_seq body.
// ---------------------------------------------------------------------------
__global__ __launch_bounds__(256)
void lstm_step(const float* __restrict__ gpt, const float* __restrict__ WhhR,
               const float* __restrict__ hcur, float* __restrict__ hnxt,
               float* __restrict__ ctg, float* __restrict__ outt,
               float* __restrict__ hn, float* __restrict__ cn, int writehn)
{
    __shared__ float Wlds[1024*16];        // 64 KB [k][j]
    __shared__ float hstage[4][2][2048];   // 64 KB per-wave dbuf [32k][64b]
    __shared__ float pacc[4][64*17];       // padded partial gates [b][j]
    __shared__ float xwlds[64*17];         // padded xW slice [b][j]
    __shared__ float hout[256];            // h_new [b*4+hj]

    const int tid  = threadIdx.x;
    const int bidx = blockIdx.x;
    const int w = tid >> 6, l = tid & 63;

    // stage W_hh slice: linear 64 KB copy, 16 x global_load_lds(16B)
    {
        const float* base = WhhR + (size_t)bidx*16384;
        #pragma unroll
        for (int i=0;i<16;++i){
            const float* s = base + i*1024 + w*256 + l*4;
            __builtin_amdgcn_global_load_lds((const __attribute__((address_space(1))) void*)s,
                (__attribute__((address_space(3))) void*)(Wlds + i*1024 + w*256), 16, 0, 0);
        }
    }
    {   // xW slice -> xwlds (padded [b][j], stride 17)
        float4 v = *reinterpret_cast<const float4*>(gpt + (size_t)bidx*1024 + tid*4);
        const int b = tid >> 2, j0 = (tid & 3)*4;
        float* xp = &xwlds[b*17 + j0];
        xp[0]=v.x; xp[1]=v.y; xp[2]=v.z; xp[3]=v.w;
    }

    const int c0 = (l & 3) << 2;
    const int b0 = (l >> 2) << 2;
    const int kbase = w << 8;
    const int bq = tid & 63;
    const int hj = tid >> 6;

    const float* hc = hcur + (size_t)kbase*64;
    float4 pre[8];
    #pragma unroll
    for (int it=0;it<8;++it)
        pre[it] = *reinterpret_cast<const float4*>(hc + it*256 + l*4);

    __syncthreads();   // drains global_load_lds (vmcnt) + lds writes

    #pragma unroll
    for (int it=0;it<8;++it)
        *reinterpret_cast<float4*>(&hstage[w][0][it*256 + l*4]) = pre[it];

    float acc[4][4];
    #pragma unroll
    for (int i2=0;i2<4;++i2){acc[i2][0]=0.f;acc[i2][1]=0.f;acc[i2][2]=0.f;acc[i2][3]=0.f;}

    for (int sc=0; sc<8; ++sc){
        if (sc < 7){
            const float* s2 = hc + (size_t)(sc+1)*2048;
            #pragma unroll
            for (int it=0;it<8;++it)
                pre[it] = *reinterpret_cast<const float4*>(s2 + it*256 + l*4);
        }
        const float* hs = hstage[w][sc&1];
        const float* wl = &Wlds[(size_t)(kbase + sc*32)*16];
        #pragma unroll
        for (int kk=0; kk<32; ++kk){
            float4 hv = *reinterpret_cast<const float4*>(&hs[kk*64 + b0]);
            float4 wv = *reinterpret_cast<const float4*>(&wl[kk*16 + c0]);
            acc[0][0]+=hv.x*wv.x; acc[0][1]+=hv.x*wv.y; acc[0][2]+=hv.x*wv.z; acc[0][3]+=hv.x*wv.w;
            acc[1][0]+=hv.y*wv.x; acc[1][1]+=hv.y*wv.y; acc[1][2]+=hv.y*wv.z; acc[1][3]+=hv.y*wv.w;
            acc[2][0]+=hv.z*wv.x; acc[2][1]+=hv.z*wv.y; acc[2][2]+=hv.z*wv.z; acc[2][3]+=hv.z*wv.w;
            acc[3][0]+=hv.w*wv.x; acc[3][1]+=hv.w*wv.y; acc[3][2]+=hv.w*wv.z; acc[3][3]+=hv.w*wv.w;
        }
        if (sc < 7){
            float* d = hstage[w][(sc+1)&1];
            #pragma unroll
            for (int it=0;it<8;++it)
                *reinterpret_cast<float4*>(&d[it*256 + l*4]) = pre[it];
        }
    }
    #pragma unroll
    for (int bi=0;bi<4;++bi){
        float* pp = &pacc[w][(b0+bi)*17 + c0];
        pp[0]=acc[bi][0]; pp[1]=acc[bi][1]; pp[2]=acc[bi][2]; pp[3]=acc[bi][3];
    }
    __syncthreads();

    {   // phase C: one thread per (batch, h-col)
        float gs[4];
        #pragma unroll
        for (int g=0; g<4; ++g){
            const int idx = bq*17 + g*4 + hj;
            gs[g] = xwlds[idx] + pacc[0][idx] + pacc[1][idx] + pacc[2][idx] + pacc[3][idx];
        }
        float ig = 1.f/(1.f + __expf(-gs[0]));
        float fg = 1.f/(1.f + __expf(-gs[1]));
        float gg = tanhf(gs[2]);
        float og = 1.f/(1.f + __expf(-gs[3]));
        float c_new = fg * ctg[bidx*256 + tid] + ig * gg;
        float h_new = og * tanhf(c_new);
        ctg[bidx*256 + tid] = c_new;
        const int hcolg = bidx*4 + hj;
        hnxt[hcolg*64 + bq] = h_new;
        hout[bq*4 + hj] = h_new;
        if (writehn){
            hn[(size_t)bq*1024 + hcolg] = h_new;
            cn[(size_t)bq*1024 + hcolg] = c_new;
        }
    }
    __syncthreads();
    if (tid < 64){
        float4 hv = *reinterpret_cast<const float4*>(&hout[tid*4]);
        *reinterpret_cast<float4*>(&outt[(size_t)tid*1024 + bidx*4]) = hv;
    }
}

// ---------------------------------------------------------------------------
extern "C" void kernel_launch(void* const* d_in, const int* in_sizes, int n_in,
                              void* d_out, int out_size, void* d_ws, size_t ws_size,
                              hipStream_t stream)
{
    const float* x    = (const float*)d_in[0];
    const float* Wih0 = (const float*)d_in[1];
    const float* Whh0 = (const float*)d_in[2];
    const float* b0   = (const float*)d_in[3];
    const float* Wih1 = (const float*)d_in[4];
    const float* Whh1 = (const float*)d_in[5];
    const float* b1   = (const float*)d_in[6];

    float* out1 = (float*)d_out;
    float* hn   = out1 + (size_t)NROWS*HDIM;      // [2][64][1024]
    float* cn   = hn + 2*BATCH*HDIM;

    // layer-0 output scratch aliases out1 (safe: each out0 chunk is consumed
    // by the layer-1 GEMM before the layer-1 step kernels overwrite it).
    float* out0 = out1;

    char* wsb = (char*)d_ws;
    float*          gp    = (float*)wsb;                               // 268,435,456 B
    unsigned short* WThi0 = (unsigned short*)(wsb + 268435456ull);     //   8,388,608
    unsigned short* WTlo0 = (unsigned short*)(wsb + 276824064ull);     //   8,388,608
    unsigned short* WThi1 = (unsigned short*)(wsb + 285212672ull);     //   8,388,608
    unsigned short* WTlo1 = (unsigned short*)(wsb + 293601280ull);     //   8,388,608
    float*          Whh0r = (float*)(wsb + 301989888ull);              //  16,777,216
    float*          Whh1r = (float*)(wsb + 318767104ull);              //  16,777,216
    float*          hta   = (float*)(wsb + 335544320ull);              //     262,144
    float*          htb   = (float*)(wsb + 335806464ull);              //     262,144
    float*          ctg   = (float*)(wsb + 336068608ull);              //     262,144

    split_transpose_w<<<dim3(128,32),256,0,stream>>>(Wih0, WThi0, WTlo0);
    split_transpose_w<<<dim3(128,32),256,0,stream>>>(Wih1, WThi1, WTlo1);
    reorder_whh<<<256,256,0,stream>>>(Whh0, Whh0r);
    reorder_whh<<<256,256,0,stream>>>(Whh1, Whh1r);

    const float*          Ain [2] = {x, out0};
    const unsigned short* Whi [2] = {WThi0, WThi1};
    const unsigned short* Wlo [2] = {WTlo0, WTlo1};
    const float*          bia [2] = {b0, b1};
    const float*          whr [2] = {Whh0r, Whh1r};
    float*                outp[2] = {out0, out1};

    for (int layer=0; layer<2; ++layer){
        hipMemsetAsync(hta, 0, 262144, stream);
        hipMemsetAsync(ctg, 0, 262144, stream);
        float* hnL = hn + (size_t)layer*BATCH*HDIM;
        float* cnL = cn + (size_t)layer*BATCH*HDIM;
        for (int chunk=0; chunk<2; ++chunk){
            gemm_xw_split<<<4096,256,0,stream>>>(
                Ain[layer] + (size_t)chunk*NSTEPS*BATCH*HDIM,
                Whi[layer], Wlo[layer], bia[layer], gp);
            for (int t=0; t<NSTEPS; ++t){
                const float* gpt = gp + (size_t)t*256*1024;
                float* outt = outp[layer] + ((size_t)(chunk*NSTEPS + t))*BATCH*HDIM;
                float* hc = (t & 1) ? htb : hta;
                float* hx = (t & 1) ? hta : htb;
                int wfin = (chunk == 1 && t == NSTEPS-1) ? 1 : 0;
                lstm_step<<<256,256,0,stream>>>(gpt, whr[layer], hc, hx, ctg,
                                                outt, hnL, cnL, wfin);
            }
        }
    }
}

// Round 9
// 35321.835 us; speedup vs baseline: 1.6163x; 1.1339x over previous
//
#include <hip/hip_runtime.h>
#include <hip/hip_bf16.h>

#define TSTEPS 512
#define NSTEPS 256          // steps per chunk
#define BATCH  64
#define HDIM   1024
#define NROWS  (TSTEPS*BATCH)   // 32768

typedef __attribute__((ext_vector_type(8))) short bf16x8;
typedef __attribute__((ext_vector_type(4))) float f32x4;

__device__ __forceinline__ unsigned short f2bf(float f){
    unsigned u = __float_as_uint(f);
    u += 0x7fffu + ((u >> 16) & 1u);
    return (unsigned short)(u >> 16);
}
__device__ __forceinline__ float bf2f(unsigned short s){
    return __uint_as_float(((unsigned)s) << 16);
}

// ---------------------------------------------------------------------------
// Fence-free broadcast grid barrier (r5 structure, proven flag mechanics).
// h data coherence comes from returning atomics + fresh-address ring reads,
// NOT from fences. __syncthreads drains vmcnt (compiler emits
// s_waitcnt vmcnt(0) before s_barrier), so arrivals happen after all h swaps
// are acked at the coherence point. Region: slots[256] at +0, rel at +320.
// ---------------------------------------------------------------------------
__device__ __forceinline__ void gridbar(unsigned int* region, unsigned int epoch){
    unsigned int* slots = region;
    unsigned int* rel   = region + 320;
    __syncthreads();    // all waves' vmem (incl. atomic swaps) drained
    if (blockIdx.x == 0){
        const int i = threadIdx.x;
        if (i > 0){     // one slot per thread, blocks 1..255
            while (__hip_atomic_load(&slots[i], __ATOMIC_RELAXED, __HIP_MEMORY_SCOPE_AGENT) < epoch)
                __builtin_amdgcn_s_sleep(2);
        }
        __syncthreads();
        if (i == 0)
            __hip_atomic_store(rel, epoch, __ATOMIC_RELAXED, __HIP_MEMORY_SCOPE_AGENT);
    } else {
        if (threadIdx.x == 0){
            unsigned int old = __hip_atomic_exchange(&slots[blockIdx.x], epoch,
                                   __ATOMIC_RELAXED, __HIP_MEMORY_SCOPE_AGENT);
            asm volatile("" :: "v"(old));   // keep returning form (ack == visible)
            while (__hip_atomic_load(rel, __ATOMIC_RELAXED, __HIP_MEMORY_SCOPE_AGENT) < epoch)
                __builtin_amdgcn_s_sleep(2);
        }
        __syncthreads();
    }
    asm volatile("" ::: "memory");  // compiler: no hoisting ring loads above
}

// ---------------------------------------------------------------------------
// W [1024][4096] fp32 -> WThi/WTlo [4096][1024] bf16 (transpose + split)
// ---------------------------------------------------------------------------
__global__ __launch_bounds__(256)
void split_transpose_w(const float* __restrict__ W,
                       unsigned short* __restrict__ WThi,
                       unsigned short* __restrict__ WTlo)
{
    __shared__ float tile[32][33];
    const int c0 = blockIdx.x * 32;
    const int k0 = blockIdx.y * 32;
    const int tx = threadIdx.x & 31, ty = threadIdx.x >> 5;
    #pragma unroll
    for (int r=0;r<4;++r)
        tile[ty + r*8][tx] = W[(size_t)(k0 + ty + r*8)*4096 + c0 + tx];
    __syncthreads();
    #pragma unroll
    for (int r=0;r<4;++r){
        float v = tile[tx][ty + r*8];
        unsigned short hi = f2bf(v);
        unsigned short lo = f2bf(v - bf2f(hi));
        WThi[(size_t)(c0 + ty + r*8)*1024 + k0 + tx] = hi;
        WTlo[(size_t)(c0 + ty + r*8)*1024 + k0 + tx] = lo;
    }
}

// ---------------------------------------------------------------------------
// W_hh [1024][4096] fp32 -> WhhR [256][1024][16] fp32, block-contiguous
// ---------------------------------------------------------------------------
__global__ __launch_bounds__(256)
void reorder_whh(const float* __restrict__ W, float* __restrict__ Wr)
{
    const int bid = blockIdx.x;
    const int tid = threadIdx.x;
    #pragma unroll
    for (int kk=0; kk<4; ++kk){
        const int k = tid*4 + kk;
        float* dst = Wr + ((size_t)bid*1024 + k)*16;
        #pragma unroll
        for (int j=0;j<16;++j)
            dst[j] = W[(size_t)k*4096 + (j>>2)*1024 + bid*4 + (j&3)];
    }
}

// ---------------------------------------------------------------------------
// Split-bf16 MFMA GEMM over one 16384-row chunk (proven structure);
// output now stored bf16 (r1-proven numerics):
//   gp[t][bid][b][j] = bf16( sum_k A[row][k]*W[k][col] + bias[col] )
// ---------------------------------------------------------------------------
__global__ __launch_bounds__(256)
void gemm_xw_split(const float* __restrict__ A,
                   const unsigned short* __restrict__ BThi,
                   const unsigned short* __restrict__ BTlo,
                   const float* __restrict__ bias, unsigned short* __restrict__ gp)
{
    __shared__ __align__(16) unsigned short Ahi[128*32];
    __shared__ __align__(16) unsigned short Alo[128*32];
    __shared__ __align__(16) unsigned short Bhi[128*32];
    __shared__ __align__(16) unsigned short Blo[128*32];

    const int tid = threadIdx.x;
    const int w = tid >> 6, l = tid & 63;
    const int bx = blockIdx.x & 31, by = blockIdx.x >> 5;
    const int row0 = by*128, col0 = bx*128;
    const int wrow = (w>>1)*64, wcol = (w&1)*64;

    const int srow  = l >> 2;
    const int skoff = (l & 3) * 8;

    const int arow  = tid >> 1;
    const int akoff = (tid & 1) * 16;
    const float* aptr = A + (size_t)(row0 + arow)*1024 + akoff;

    f32x4 acc[4][4];
    #pragma unroll
    for (int m=0;m<4;++m)
        #pragma unroll
        for (int n=0;n<4;++n)
            acc[m][n] = (f32x4){0.f,0.f,0.f,0.f};

    for (int k0=0; k0<1024; k0+=32){
        #pragma unroll
        for (int c=0;c<2;++c){
            const int i = w*2 + c;
            const unsigned short* gh = BThi + (size_t)(col0 + i*16 + srow)*1024 + k0 + skoff;
            const unsigned short* gl = BTlo + (size_t)(col0 + i*16 + srow)*1024 + k0 + skoff;
            __builtin_amdgcn_global_load_lds((const __attribute__((address_space(1))) void*)gh,
                (__attribute__((address_space(3))) void*)(Bhi + i*512), 16, 0, 0);
            __builtin_amdgcn_global_load_lds((const __attribute__((address_space(1))) void*)gl,
                (__attribute__((address_space(3))) void*)(Blo + i*512), 16, 0, 0);
        }
        {
            float4 x0 = *reinterpret_cast<const float4*>(aptr + k0);
            float4 x1 = *reinterpret_cast<const float4*>(aptr + k0 + 4);
            float4 x2 = *reinterpret_cast<const float4*>(aptr + k0 + 8);
            float4 x3 = *reinterpret_cast<const float4*>(aptr + k0 + 12);
            float xs[16] = {x0.x,x0.y,x0.z,x0.w, x1.x,x1.y,x1.z,x1.w,
                            x2.x,x2.y,x2.z,x2.w, x3.x,x3.y,x3.z,x3.w};
            unsigned short hs[16], ls[16];
            #pragma unroll
            for (int e=0;e<16;++e){
                hs[e] = f2bf(xs[e]);
                ls[e] = f2bf(xs[e] - bf2f(hs[e]));
            }
            #pragma unroll
            for (int q=0;q<4;++q){
                ushort4 h4; h4.x=hs[q*4]; h4.y=hs[q*4+1]; h4.z=hs[q*4+2]; h4.w=hs[q*4+3];
                ushort4 l4; l4.x=ls[q*4]; l4.y=ls[q*4+1]; l4.z=ls[q*4+2]; l4.w=ls[q*4+3];
                *reinterpret_cast<ushort4*>(&Ahi[arow*32 + akoff + q*4]) = h4;
                *reinterpret_cast<ushort4*>(&Alo[arow*32 + akoff + q*4]) = l4;
            }
        }
        __syncthreads();
        bf16x8 afh[4], afl[4], bfh[4], bfl[4];
        #pragma unroll
        for (int m=0;m<4;++m){
            const int off = (wrow + m*16 + (l&15))*32 + (l>>4)*8;
            afh[m] = *reinterpret_cast<const bf16x8*>(&Ahi[off]);
            afl[m] = *reinterpret_cast<const bf16x8*>(&Alo[off]);
        }
        #pragma unroll
        for (int n=0;n<4;++n){
            const int off = (wcol + n*16 + (l&15))*32 + (l>>4)*8;
            bfh[n] = *reinterpret_cast<const bf16x8*>(&Bhi[off]);
            bfl[n] = *reinterpret_cast<const bf16x8*>(&Blo[off]);
        }
        #pragma unroll
        for (int m=0;m<4;++m)
            #pragma unroll
            for (int n=0;n<4;++n){
                acc[m][n] = __builtin_amdgcn_mfma_f32_16x16x32_bf16(afh[m], bfh[n], acc[m][n], 0,0,0);
                acc[m][n] = __builtin_amdgcn_mfma_f32_16x16x32_bf16(afl[m], bfh[n], acc[m][n], 0,0,0);
                acc[m][n] = __builtin_amdgcn_mfma_f32_16x16x32_bf16(afh[m], bfl[n], acc[m][n], 0,0,0);
            }
        __syncthreads();
    }

    #pragma unroll
    for (int n=0;n<4;++n){
        const int n_g = col0 + wcol + n*16 + (l&15);
        const float bv = bias[n_g];
        const int g = n_g >> 10, hcol = n_g & 1023;
        const int bid = hcol >> 2, hj = hcol & 3;
        #pragma unroll
        for (int m=0;m<4;++m){
            #pragma unroll
            for (int r=0;r<4;++r){
                const int m_g = row0 + wrow + m*16 + (l>>4)*4 + r;
                const int t = m_g >> 6, b = m_g & 63;
                gp[(((size_t)t*256 + bid)*64 + b)*16 + g*4 + hj] = f2bf(acc[m][n][r] + bv);
            }
        }
    }
}

// ---------------------------------------------------------------------------
// Persistent recurrence over one 256-step chunk — fp32 arithmetic (r4 body),
// W_hh resident in LDS, h exchanged through a 257-slot ring:
//   write slot t via returning 64-bit atomic swaps (ack == at coherence point)
//   read  slot t-1 via PLAIN loads (first touch per kernel instance -> fresh)
// Block owns h-cols [bidx*4, bidx*4+4). c-state in a register, ctg between chunks.
// ---------------------------------------------------------------------------
__global__ __launch_bounds__(256)
void lstm_ring(const unsigned short* __restrict__ gp, const float* __restrict__ WhhR,
               float* __restrict__ out, float* __restrict__ ring,
               float* __restrict__ ctg, float* __restrict__ hn, float* __restrict__ cn,
               unsigned int* __restrict__ bar, int first, int last)
{
    __shared__ float Wlds[1024*16];        // 64 KB [k][j]
    __shared__ float hstage[4][2][2048];   // 64 KB per-wave dbuf [32k][64b]
    __shared__ float pacc[4][64*17];       // padded partial gates [b][j]
    __shared__ float xwlds[64*17];         // padded xW slice [b][j]
    __shared__ float hout[256];            // h_new [b*4+hj]

    const int tid  = threadIdx.x;
    const int bidx = blockIdx.x;
    const int w = tid >> 6, l = tid & 63;

    {   // stage W_hh slice once per chunk: 16 x global_load_lds(16B)
        const float* base = WhhR + (size_t)bidx*16384;
        #pragma unroll
        for (int i=0;i<16;++i){
            const float* s = base + i*1024 + w*256 + l*4;
            __builtin_amdgcn_global_load_lds((const __attribute__((address_space(1))) void*)s,
                (__attribute__((address_space(3))) void*)(Wlds + i*1024 + w*256), 16, 0, 0);
        }
    }
    float creg = first ? 0.f : ctg[bidx*256 + tid];
    if (first){   // zero slot 256 (h_{-1}) for our columns, returning swaps
        const int colg = bidx*4 + (tid>>6);
        unsigned int old = __hip_atomic_exchange(
            (unsigned int*)(ring + (size_t)256*65536 + colg*64 + (tid&63)),
            0u, __ATOMIC_RELAXED, __HIP_MEMORY_SCOPE_AGENT);
        asm volatile("" :: "v"(old));
    }
    gridbar(bar, 1);   // zero-slot at L3 + W LDS staged (syncthreads drains)

    const int c0 = (l & 3) << 2;
    const int b0 = (l >> 2) << 2;
    const int kbase = w << 8;
    const int bq = tid & 63;
    const int hj = tid >> 6;

    for (int t=0; t<NSTEPS; ++t){
        {   // xW[t] slice (bf16) -> xwlds (padded [b][j], stride 17)
            ushort4 v = *reinterpret_cast<const ushort4*>(gp + ((size_t)t*256 + bidx)*1024 + tid*4);
            const int b = tid >> 2, j0 = (tid & 3)*4;
            float* xp = &xwlds[b*17 + j0];
            xp[0]=bf2f(v.x); xp[1]=bf2f(v.y); xp[2]=bf2f(v.z); xp[3]=bf2f(v.w);
        }

        const int rs = (t > 0) ? (t-1) : (first ? 256 : NSTEPS-1);
        const float* hc = ring + (size_t)rs*65536 + (size_t)kbase*64;
        float4 pre[8];
        #pragma unroll
        for (int it=0;it<8;++it)
            pre[it] = *reinterpret_cast<const float4*>(hc + it*256 + l*4);
        #pragma unroll
        for (int it=0;it<8;++it)
            *reinterpret_cast<float4*>(&hstage[w][0][it*256 + l*4]) = pre[it];

        float acc[4][4];
        #pragma unroll
        for (int i2=0;i2<4;++i2){acc[i2][0]=0.f;acc[i2][1]=0.f;acc[i2][2]=0.f;acc[i2][3]=0.f;}

        for (int sc=0; sc<8; ++sc){
            if (sc < 7){
                const float* s2 = hc + (size_t)(sc+1)*2048;
                #pragma unroll
                for (int it=0;it<8;++it)
                    pre[it] = *reinterpret_cast<const float4*>(s2 + it*256 + l*4);
            }
            const float* hs = hstage[w][sc&1];
            const float* wl = &Wlds[(size_t)(kbase + sc*32)*16];
            #pragma unroll
            for (int kk=0; kk<32; ++kk){
                float4 hv = *reinterpret_cast<const float4*>(&hs[kk*64 + b0]);
                float4 wv = *reinterpret_cast<const float4*>(&wl[kk*16 + c0]);
                acc[0][0]+=hv.x*wv.x; acc[0][1]+=hv.x*wv.y; acc[0][2]+=hv.x*wv.z; acc[0][3]+=hv.x*wv.w;
                acc[1][0]+=hv.y*wv.x; acc[1][1]+=hv.y*wv.y; acc[1][2]+=hv.y*wv.z; acc[1][3]+=hv.y*wv.w;
                acc[2][0]+=hv.z*wv.x; acc[2][1]+=hv.z*wv.y; acc[2][2]+=hv.z*wv.z; acc[2][3]+=hv.z*wv.w;
                acc[3][0]+=hv.w*wv.x; acc[3][1]+=hv.w*wv.y; acc[3][2]+=hv.w*wv.z; acc[3][3]+=hv.w*wv.w;
            }
            if (sc < 7){
                float* d = hstage[w][(sc+1)&1];
                #pragma unroll
                for (int it=0;it<8;++it)
                    *reinterpret_cast<float4*>(&d[it*256 + l*4]) = pre[it];
            }
        }
        #pragma unroll
        for (int bi=0;bi<4;++bi){
            float* pp = &pacc[w][(b0+bi)*17 + c0];
            pp[0]=acc[bi][0]; pp[1]=acc[bi][1]; pp[2]=acc[bi][2]; pp[3]=acc[bi][3];
        }
        __syncthreads();

        {   // phase C: one thread per (batch, h-col)
            float gs[4];
            #pragma unroll
            for (int g=0; g<4; ++g){
                const int idx = bq*17 + g*4 + hj;
                gs[g] = xwlds[idx] + pacc[0][idx] + pacc[1][idx] + pacc[2][idx] + pacc[3][idx];
            }
            float ig = 1.f/(1.f + __expf(-gs[0]));
            float fg = 1.f/(1.f + __expf(-gs[1]));
            float gg = tanhf(gs[2]);
            float og = 1.f/(1.f + __expf(-gs[3]));
            float c_new = fg * creg + ig * gg;
            float h_new = og * tanhf(c_new);
            creg = c_new;
            hout[bq*4 + hj] = h_new;
            if (last && t == NSTEPS-1){
                const int hcolg = bidx*4 + hj;
                hn[(size_t)bq*1024 + hcolg] = h_new;
                cn[(size_t)bq*1024 + hcolg] = c_new;
            }
        }
        __syncthreads();

        {   // publish h[t]: 128 x 64-bit returning swaps (ack == at L3)
            float* ringw = ring + (size_t)t*65536;
            if (tid < 128){
                const int coll = tid & 3;
                const int b0p  = (tid >> 2) << 1;
                float v0 = hout[b0p*4 + coll];
                float v1 = hout[(b0p+1)*4 + coll];
                unsigned long long pk =
                    ((unsigned long long)__float_as_uint(v1) << 32) | __float_as_uint(v0);
                unsigned long long old = __hip_atomic_exchange(
                    reinterpret_cast<unsigned long long*>(ringw + (bidx*4 + coll)*64 + b0p),
                    pk, __ATOMIC_RELAXED, __HIP_MEMORY_SCOPE_AGENT);
                asm volatile("" :: "v"(old));
            }
            if (tid < 64){
                float4 hv = *reinterpret_cast<const float4*>(&hout[tid*4]);
                *reinterpret_cast<float4*>(&out[(size_t)t*65536 + (size_t)tid*1024 + bidx*4]) = hv;
            }
        }
        gridbar(bar, t + 2);   // syncthreads inside drains the swaps first
    }
    ctg[bidx*256 + tid] = creg;
}

// ---------------------------------------------------------------------------
extern "C" void kernel_launch(void* const* d_in, const int* in_sizes, int n_in,
                              void* d_out, int out_size, void* d_ws, size_t ws_size,
                              hipStream_t stream)
{
    const float* x    = (const float*)d_in[0];
    const float* Wih0 = (const float*)d_in[1];
    const float* Whh0 = (const float*)d_in[2];
    const float* b0   = (const float*)d_in[3];
    const float* Wih1 = (const float*)d_in[4];
    const float* Whh1 = (const float*)d_in[5];
    const float* b1   = (const float*)d_in[6];

    float* out1 = (float*)d_out;
    float* hn   = out1 + (size_t)NROWS*HDIM;      // [2][64][1024]
    float* cn   = hn + 2*BATCH*HDIM;

    // layer-0 output scratch aliases out1 (safe: each out0 chunk is consumed
    // by the layer-1 GEMM before the layer-1 steps overwrite it).
    float* out0 = out1;

    char* wsb = (char*)d_ws;
    unsigned short* gp    = (unsigned short*)wsb;                      // 134,217,728 B
    unsigned short* WThi0 = (unsigned short*)(wsb + 134217728ull);     //   8,388,608
    unsigned short* WTlo0 = (unsigned short*)(wsb + 142606336ull);     //   8,388,608
    unsigned short* WThi1 = (unsigned short*)(wsb + 150994944ull);     //   8,388,608
    unsigned short* WTlo1 = (unsigned short*)(wsb + 159383552ull);     //   8,388,608
    float*          Whh0r = (float*)(wsb + 167772160ull);              //  16,777,216
    float*          Whh1r = (float*)(wsb + 184549376ull);              //  16,777,216
    float*          ring  = (float*)(wsb + 201326592ull);              //  67,371,008 (257 slots)
    float*          ctg   = (float*)(wsb + 268697600ull);              //     262,144
    unsigned int*   bar   = (unsigned int*)(wsb + 268959744ull);       //       8,192

    hipMemsetAsync(bar, 0, 4*512*sizeof(unsigned int), stream);
    split_transpose_w<<<dim3(128,32),256,0,stream>>>(Wih0, WThi0, WTlo0);
    split_transpose_w<<<dim3(128,32),256,0,stream>>>(Wih1, WThi1, WTlo1);
    reorder_whh<<<256,256,0,stream>>>(Whh0, Whh0r);
    reorder_whh<<<256,256,0,stream>>>(Whh1, Whh1r);

    const float*          Ain [2] = {x, out0};
    const unsigned short* Whi [2] = {WThi0, WThi1};
    const unsigned short* Wlo [2] = {WTlo0, WTlo1};
    const float*          bia [2] = {b0, b1};
    const float*          whr [2] = {Whh0r, Whh1r};
    float*                outp[2] = {out0, out1};

    for (int layer=0; layer<2; ++layer){
        float* hnL = hn + (size_t)layer*BATCH*HDIM;
        float* cnL = cn + (size_t)layer*BATCH*HDIM;
        for (int chunk=0; chunk<2; ++chunk){
            gemm_xw_split<<<4096,256,0,stream>>>(
                Ain[layer] + (size_t)chunk*NSTEPS*BATCH*HDIM,
                Whi[layer], Wlo[layer], bia[layer], gp);

            const unsigned short* gpc = gp;
            const float* wh = whr[layer];
            float* op = outp[layer] + (size_t)chunk*NSTEPS*BATCH*HDIM;
            float* rg = ring; float* cg_ = ctg;
            unsigned int* br = bar + (size_t)(layer*2 + chunk)*512;
            int first = (chunk == 0), last = (chunk == 1);
            void* args[10] = {(void*)&gpc, (void*)&wh, (void*)&op, (void*)&rg,
                              (void*)&cg_, (void*)&hnL, (void*)&cnL,
                              (void*)&br, (void*)&first, (void*)&last};
            hipLaunchCooperativeKernel(reinterpret_cast<void*>(&lstm_ring),
                                       dim3(256), dim3(256), args, 0, stream);
        }
    }
}